// Round 1
// baseline (1400.977 us; speedup 1.0000x reference)
//
#include <hip/hip_runtime.h>
#include <math.h>

// DelayAndSum: out[b,t] = (1/S) * sum_s x[b, t+d_s, s] * (t+d_s < T)
// B=16, T=100000, S=128, d_s = rint(s*sin(ANGLE)/2) in [0,32].
//
// Strategy: per block, process one b and a tile of TT=256 t-values.
// Phase 1: stream rows [t0, t0+TT+32) coalesced (float4/lane), reduce each
//          row's 128 sensors into 33 per-delay group sums in LDS (runs of
//          equal delay are contiguous, length 3-5 => <=2 LDS atomics/float4).
// Phase 2: out[b,t] = (1/S) * sum_{delta=0..32} P[t - t0 + delta][delta].
// Rows >= T are left zero => implements the validity mask exactly.

#define SENS 128
#define TT   256
#define ROWS (TT + 32)        // 288 rows per tile (max delay = 32)
#define NG   33               // delay groups 0..32
#define LSTR 33               // LDS row stride (odd -> 2-way bank alias, free)

struct DelayTab { int d[SENS]; };

__global__ __launch_bounds__(256)
void das_kernel(const float* __restrict__ x, float* __restrict__ out,
                DelayTab tab, int T) {
    __shared__ float P[ROWS * LSTR];   // 288*33*4 = 38016 B -> 4 blocks/CU

    const int tid = threadIdx.x;
    const int b   = blockIdx.y;
    const int t0  = blockIdx.x * TT;

    // zero-init group sums
    for (int i = tid; i < ROWS * LSTR; i += 256) P[i] = 0.0f;
    __syncthreads();

    // Each thread owns a fixed 4-sensor chunk (c4..c4+3) across all sweeps:
    // flat = sweep*1024 + tid*4, and 1024 % 128 == 0, so the sensor index is
    // constant per thread. Hoist the delay lookups out of the loop.
    const int c4 = (tid & 31) * 4;
    const int d0 = tab.d[c4 + 0];
    const int d1 = tab.d[c4 + 1];
    const int d2 = tab.d[c4 + 2];
    const int d3 = tab.d[c4 + 3];

    const float* __restrict__ xb = x + (size_t)b * (size_t)T * SENS;

    // Phase 1: 36 sweeps, 8 rows/sweep (32 lanes of float4 cover one row).
    #pragma unroll 4
    for (int sweep = 0; sweep < ROWS / 8; ++sweep) {
        const int r = sweep * 8 + (tid >> 5);
        const int u = t0 + r;
        if (u < T) {
            const float4 v = *(const float4*)(xb + (size_t)u * SENS + c4);
            float* Pr = P + r * LSTR;
            // delays are nondecreasing in s: run-length merge the 4 values
            float run = v.x; int cur = d0;
            if (d1 == cur) run += v.y; else { atomicAdd(&Pr[cur], run); cur = d1; run = v.y; }
            if (d2 == cur) run += v.z; else { atomicAdd(&Pr[cur], run); cur = d2; run = v.z; }
            if (d3 == cur) run += v.w; else { atomicAdd(&Pr[cur], run); cur = d3; run = v.w; }
            atomicAdd(&Pr[cur], run);
        }
    }
    __syncthreads();

    // Phase 2: each thread produces one output t.
    const int t = t0 + tid;
    if (t < T) {
        float acc = 0.0f;
        #pragma unroll
        for (int dlt = 0; dlt < NG; ++dlt)
            acc += P[(tid + dlt) * LSTR + dlt];
        out[(size_t)b * T + t] = acc * (1.0f / SENS);
    }
}

extern "C" void kernel_launch(void* const* d_in, const int* in_sizes, int n_in,
                              void* d_out, int out_size, void* d_ws, size_t ws_size,
                              hipStream_t stream) {
    const float* x = (const float*)d_in[0];
    float* out = (float*)d_out;

    const int B = 16;
    const int T = in_sizes[0] / (B * SENS);   // 100000

    // Replicate numpy's delay computation exactly on the host:
    // np.round(np.arange(S) * np.sin(ANGLE) / 2.0).astype(int32)
    // np.sin -> libm sin (same machine/libm as the reference),
    // np.round(decimals=0) -> rint (round half to even, default FE mode).
    DelayTab tab;
    const double sv = sin(0.5235987755982988);
    for (int s = 0; s < SENS; ++s) {
        tab.d[s] = (int)rint((double)s * sv / 2.0);
    }

    dim3 grid((T + TT - 1) / TT, B);
    dim3 block(256);
    das_kernel<<<grid, block, 0, stream>>>(x, out, tab, T);
}

// Round 2
// 1007.065 us; speedup vs baseline: 1.3911x; 1.3911x over previous
//
#include <hip/hip_runtime.h>
#include <math.h>

// DelayAndSum: out[b,t] = (1/S) * sum_s x[b, t+d_s, s] * (t+d_s < T)
// B=16, T=100000, S=128, d_s = rint(s*sin(ANGLE)/2) in [0,32].
//
// R2: atomic-free. Delays are nondecreasing, runs of equal delay are 3-5
// long, so each lane's fixed 4-sensor chunk spans <=2 delay groups with a
// fixed split. Phase 1 streams rows coalesced (float4/lane), each lane
// computes two run-sums in registers and stores them to PRIVATE LDS slots
// (slot-major, no read-modify-write, no collisions):
//    P[(2L)*RSTR   + r] = sum of chunk-L elems in first group  (delay dA_L)
//    P[(2L+1)*RSTR + r] = sum of chunk-L elems in second group (delay dB_L)
// Phase 2: out[t0+tid] = (1/S) * sum_{j=0..63} P[tid + off[j]] where
// off[j] = slot_j*RSTR + d_slot_j is host-precomputed (uniform scalars).
// Rows >= T are zeroed (tail block only) => exact validity mask.

#define SENS 128
#define TT   256
#define ROWS (TT + 32)        // 288 rows per tile (max delay = 32)
#define RSTR (ROWS + 1)       // 289: odd stride -> <=2-way bank alias (free)
#define NSLOT 64              // 2 slots per 4-sensor chunk

struct Tabs {
    int off[NSLOT];           // phase-2 combined offsets (uniform)
    unsigned cm1, cm2, cm3;   // per-lane "sensor j in first group" bitmasks
};

__global__ __launch_bounds__(256)
void das2_kernel(const float* __restrict__ x, float* __restrict__ out,
                 Tabs tb, int T) {
    __shared__ float P[NSLOT * RSTR];   // 64*289*4 = 73984 B -> 2 blocks/CU

    const int tid = threadIdx.x;
    const int b   = blockIdx.y;
    const int t0  = blockIdx.x * TT;

    const int L = tid & 31;                       // chunk id (sensors 4L..4L+3)
    const bool c1 = (tb.cm1 >> L) & 1u;           // d[4L+1]==d[4L]
    const bool c2 = (tb.cm2 >> L) & 1u;           // d[4L+2]==d[4L]
    const bool c3 = (tb.cm3 >> L) & 1u;           // d[4L+3]==d[4L]
    const int rb = tid >> 5;                      // row-within-sweep (0..7)
    float* __restrict__ Pw = P + (2 * L) * RSTR;
    const float* __restrict__ xb = x + (size_t)b * (size_t)T * SENS + 4 * L;

    if (t0 + ROWS <= T) {
        // hot path: no bounds checks, 36 independent float4 loads pipelined
        #pragma unroll 4
        for (int sw = 0; sw < ROWS / 8; ++sw) {
            const int r = sw * 8 + rb;
            const float4 v = *(const float4*)(xb + (size_t)(t0 + r) * SENS);
            float a = v.x;
            a += c1 ? v.y : 0.0f;
            a += c2 ? v.z : 0.0f;
            a += c3 ? v.w : 0.0f;
            const float g = (c1 ? 0.0f : v.y) + (c2 ? 0.0f : v.z)
                          + (c3 ? 0.0f : v.w);
            Pw[r]        = a;   // plain ds_write_b32, private address
            Pw[RSTR + r] = g;   // +1156B imm offset
        }
    } else {
        // tail block: rows past T stay zero (implements the validity mask)
        for (int i = tid; i < NSLOT * RSTR; i += 256) P[i] = 0.0f;
        __syncthreads();
        for (int sw = 0; sw < ROWS / 8; ++sw) {
            const int r = sw * 8 + rb;
            const int u = t0 + r;
            if (u < T) {
                const float4 v = *(const float4*)(xb + (size_t)u * SENS);
                float a = v.x;
                a += c1 ? v.y : 0.0f;
                a += c2 ? v.z : 0.0f;
                a += c3 ? v.w : 0.0f;
                const float g = (c1 ? 0.0f : v.y) + (c2 ? 0.0f : v.z)
                              + (c3 ? 0.0f : v.w);
                Pw[r]        = a;
                Pw[RSTR + r] = g;
            }
        }
    }
    __syncthreads();

    // Phase 2: one output per thread; 64 conflict-free LDS reads.
    const int t = t0 + tid;
    if (t < T) {
        float acc = 0.0f;
        #pragma unroll
        for (int j = 0; j < NSLOT; ++j)
            acc += P[tid + tb.off[j]];
        out[(size_t)b * T + t] = acc * (1.0f / SENS);
    }
}

extern "C" void kernel_launch(void* const* d_in, const int* in_sizes, int n_in,
                              void* d_out, int out_size, void* d_ws, size_t ws_size,
                              hipStream_t stream) {
    const float* x = (const float*)d_in[0];
    float* out = (float*)d_out;

    const int B = 16;
    const int T = in_sizes[0] / (B * SENS);   // 100000

    // Replicate numpy's delay computation exactly on the host (libm sin,
    // rint = round-half-even). This passed validation in R1.
    int d[SENS];
    const double sv = sin(0.5235987755982988);
    for (int s = 0; s < SENS; ++s)
        d[s] = (int)rint((double)s * sv / 2.0);

    Tabs tb;
    tb.cm1 = tb.cm2 = tb.cm3 = 0u;
    for (int L = 0; L < 32; ++L) {
        const int d0 = d[4 * L + 0], d1 = d[4 * L + 1];
        const int d2 = d[4 * L + 2], d3 = d[4 * L + 3];
        if (d1 == d0) tb.cm1 |= 1u << L;
        if (d2 == d0) tb.cm2 |= 1u << L;
        if (d3 == d0) tb.cm3 |= 1u << L;
        // slot 2L holds group dA=d0, slot 2L+1 holds group dB=d3
        // (if the chunk is single-group, slot 2L+1 holds 0 and dB==d0: adding
        //  the zero at row tid+dB is harmless and in-bounds)
        tb.off[2 * L + 0] = (2 * L + 0) * RSTR + d0;
        tb.off[2 * L + 1] = (2 * L + 1) * RSTR + d3;
    }

    dim3 grid((T + TT - 1) / TT, B);
    dim3 block(256);
    das2_kernel<<<grid, block, 0, stream>>>(x, out, tb, T);
}